// Round 2
// baseline (627.642 us; speedup 1.0000x reference)
//
#include <hip/hip_runtime.h>
#include <math.h>

#define B_ 2
#define C_ 128
#define NPIX_ 16384
#define HTH_ 184
#define HTW_ 180
#define NBINS_ 33120
#define NSPH_ 16384
#define NPB_ 1984
#define TOTN_ 3968
#define EPS_ 1e-5f

// stats region layout (floats), first 652 are zeroed each launch
#define ST_HC_SUM 0
#define ST_HC_SQ  128
#define ST_SC_SUM 256
#define ST_SC_SQ  448
#define ST_LOSS   640
#define ST_IMG_A  704
#define ST_IMG_D  832
#define ST_HC_A   960
#define ST_HC_D   1088
#define ST_SC_A   1216
#define ST_SC_D   1408

// ---------------- K1: per-channel BN stats of image -> a,d ----------------
__global__ void k1_img_stats(const float* __restrict__ img, const float* __restrict__ g,
                             const float* __restrict__ be, float* __restrict__ st) {
  int c = blockIdx.x; int tid = threadIdx.x;
  float s1 = 0.f, s2 = 0.f;
  for (int i = tid; i < B_*NPIX_; i += 256) {
    int b = i >> 14, p = i & (NPIX_-1);
    float v = img[((size_t)(b*C_ + c))*NPIX_ + p];
    s1 += v; s2 += v*v;
  }
  __shared__ float r1[256], r2[256];
  r1[tid] = s1; r2[tid] = s2; __syncthreads();
  for (int off = 128; off; off >>= 1) {
    if (tid < off) { r1[tid] += r1[tid+off]; r2[tid] += r2[tid+off]; }
    __syncthreads();
  }
  if (tid == 0) {
    float n = (float)(B_*NPIX_);
    float m = r1[0]/n; float var = r2[0]/n - m*m;
    float a = g[c]*rsqrtf(var + EPS_);
    st[ST_IMG_A + c] = a;
    st[ST_IMG_D + c] = be[c] - a*m;
  }
}

// ---------------- K2: BN+ReLU + transpose NCHW -> [b][pix][c] ----------------
__global__ void k2_bnrelu_t(const float* __restrict__ img, const float* __restrict__ st,
                            float* __restrict__ xt) {
  __shared__ float tile[32*65];
  int p0 = blockIdx.x*64, c0 = blockIdx.y*32, b = blockIdx.z;
  int tid = threadIdx.x;
  for (int r = 0; r < 8; r++) {
    int flat = tid + r*256;
    int row = flat >> 6, col = flat & 63;
    int c = c0 + row;
    float v = img[((size_t)(b*C_ + c))*NPIX_ + p0 + col];
    tile[row*65 + col] = fmaxf(st[ST_IMG_A + c]*v + st[ST_IMG_D + c], 0.f);
  }
  __syncthreads();
  for (int r = 0; r < 8; r++) {
    int flat = tid + r*256;
    int pl = flat >> 5, cl = flat & 31;
    xt[((size_t)b*NPIX_ + p0 + pl)*C_ + c0 + cl] = tile[cl*65 + pl];
  }
}

// ---------------- K3: Hough gather -> ht_t[b][bin][c] ----------------
__global__ void k3_hough(const float* __restrict__ xt, const int* __restrict__ hidx,
                         const float* __restrict__ hwt, float* __restrict__ ht) {
  int tid = threadIdx.x;
  int bin = blockIdx.x*2 + (tid >> 7);
  int b = blockIdx.y;
  int c = tid & 127;
  float acc = 0.f;
  #pragma unroll
  for (int k = 0; k < 8; k++) {
    int p = hidx[bin*8 + k];
    float w = hwt[bin*8 + k];
    acc += w * xt[((size_t)b*NPIX_ + p)*C_ + c];
  }
  ht[((size_t)b*NBINS_ + bin)*C_ + c] = acc;
}

// ---------------- K4: 3x3 conv SAME, NHWC, fp32 ----------------
// tile: 36 px (x) * 128 co per block; thread: 9 px * 2 co
__global__ __launch_bounds__(256) void k4_conv(
    const float* __restrict__ ht, const float* __restrict__ w, float* __restrict__ hc) {
  __shared__ float sIn[38*128];
  int tid = threadIdx.x;
  int co2 = (tid & 63)*2;
  int ph = tid >> 6;
  int P0 = ph*9;
  int x0 = blockIdx.x*36;
  int y = blockIdx.y;
  int b = blockIdx.z;
  float2 acc[9];
  #pragma unroll
  for (int p = 0; p < 9; p++) acc[p] = make_float2(0.f, 0.f);
  for (int dy = 0; dy < 3; dy++) {
    int yy = y + dy - 1;
    if (yy < 0 || yy >= HTH_) continue;     // block-uniform
    __syncthreads();
    for (int r = 0; r < 19; r++) {
      int flat = tid + r*256;               // covers 38*128 = 4864
      int px = flat >> 7, ci = flat & 127;
      int xg = x0 - 1 + px;
      sIn[flat] = (xg >= 0 && xg < HTW_) ? ht[((size_t)b*NBINS_ + yy*HTW_ + xg)*C_ + ci] : 0.f;
    }
    __syncthreads();
    for (int ci = 0; ci < 128; ci += 4) {
      float4 in4[11];
      #pragma unroll
      for (int i = 0; i < 11; i++) in4[i] = *(const float4*)&sIn[(P0+i)*128 + ci];
      #pragma unroll
      for (int dx = 0; dx < 3; dx++) {
        const float* wp = w + ((dy*3+dx)*128 + ci)*128 + co2;
        float2 w0 = *(const float2*)(wp);
        float2 w1 = *(const float2*)(wp + 128);
        float2 w2 = *(const float2*)(wp + 256);
        float2 w3 = *(const float2*)(wp + 384);
        #pragma unroll
        for (int p = 0; p < 9; p++) {
          float4 iv = in4[p+dx];
          acc[p].x += iv.x*w0.x + iv.y*w1.x + iv.z*w2.x + iv.w*w3.x;
          acc[p].y += iv.x*w0.y + iv.y*w1.y + iv.z*w2.y + iv.w*w3.y;
        }
      }
    }
  }
  #pragma unroll
  for (int p = 0; p < 9; p++) {
    int col = x0 + P0 + p;
    *(float2*)&hc[((size_t)b*NBINS_ + y*HTW_ + col)*C_ + co2] = acc[p];
  }
}

// ---------------- K5: hc BN stats (atomic accumulate) ----------------
__global__ void k5_hc_stats(const float* __restrict__ hc, float* __restrict__ st) {
  int tid = threadIdx.x; int c = tid & 127;
  float s1 = 0.f, s2 = 0.f;
  for (int row = blockIdx.x*2 + (tid >> 7); row < B_*NBINS_; row += 1024) {
    float v = hc[(size_t)row*C_ + c];
    s1 += v; s2 += v*v;
  }
  __shared__ float r[256];
  r[tid] = s1; __syncthreads();
  if (tid < 128) atomicAdd(&st[ST_HC_SUM + c], r[tid] + r[tid+128]);
  __syncthreads();
  r[tid] = s2; __syncthreads();
  if (tid < 128) atomicAdd(&st[ST_HC_SQ + c], r[tid] + r[tid+128]);
}

__global__ void k5b_hc_fin(const float* __restrict__ g, const float* __restrict__ be,
                           float* __restrict__ st) {
  int c = threadIdx.x;
  float n = (float)(B_*NBINS_);
  float m = st[ST_HC_SUM+c]/n;
  float var = st[ST_HC_SQ+c]/n - m*m;
  float a = g[c]*rsqrtf(var + EPS_);
  st[ST_HC_A+c] = a; st[ST_HC_D+c] = be[c] - a*m;
}

// ---------------- K6: sphere gather with fused BN+ReLU of hc ----------------
__global__ void k6_sphere(const float* __restrict__ hc, const float* __restrict__ st,
                          const int* __restrict__ sph_idx, const float* __restrict__ sph_w,
                          const int* __restrict__ ind0, const int* __restrict__ ind1,
                          const int* __restrict__ ind2, float* __restrict__ out) {
  int gn = blockIdx.x; int c = threadIdx.x;
  int b = gn / NPB_, nb = gn % NPB_;
  int v;
  if (nb < 1024) v = ind0[b*1024 + nb];
  else if (nb < 1792) v = ind1[b*768 + nb - 1024];
  else v = ind2[b*192 + nb - 1792];
  float a = st[ST_HC_A + c], d = st[ST_HC_D + c];
  float acc = 0.f;
  #pragma unroll
  for (int k = 0; k < 16; k++) {
    int mi = sph_idx[v*16 + k];
    float mw = sph_w[v*16 + k];
    float hv = hc[((size_t)b*NBINS_ + mi)*C_ + c];
    acc += mw * fmaxf(a*hv + d, 0.f);
  }
  out[(size_t)gn*C_ + c] = acc;
}

// ---------------- K7: 1x1 sconv [128->64] + BN stat accumulation ----------------
__global__ __launch_bounds__(256) void k7_sconv(
    const float* __restrict__ xin, const float* __restrict__ w_sc,
    const float* __restrict__ b_sc, float* __restrict__ y, float* __restrict__ st) {
  __shared__ float xs[32*128];
  __shared__ float wT[128*65];
  __shared__ float red[256];
  int tid = threadIdx.x;
  int gn0 = blockIdx.x * 32;
  int nb = gn0 % NPB_;
  int s = nb < 1024 ? 0 : (nb < 1792 ? 1 : 2);   // block scale-uniform (32-aligned)
  for (int r = 0; r < 16; r++) {
    int flat = tid + r*256;
    xs[flat] = xin[(size_t)gn0*C_ + flat];
  }
  for (int r = 0; r < 32; r++) {
    int flat = tid + r*256;
    int o = flat >> 7, cc = flat & 127;
    wT[cc*65 + o] = w_sc[(s*64 + o)*C_ + cc];
  }
  __syncthreads();
  int o = tid & 63, nl = tid >> 6;
  float bias = b_sc[s*64 + o];
  float acc[8];
  #pragma unroll
  for (int i = 0; i < 8; i++) acc[i] = bias;
  for (int cc = 0; cc < 128; cc++) {
    float wv = wT[cc*65 + o];
    #pragma unroll
    for (int i = 0; i < 8; i++)
      acc[i] += xs[(nl*8 + i)*128 + cc] * wv;
  }
  float s1 = 0.f, s2 = 0.f;
  #pragma unroll
  for (int i = 0; i < 8; i++) {
    y[(size_t)(gn0 + nl*8 + i)*64 + o] = acc[i];
    s1 += acc[i]; s2 += acc[i]*acc[i];
  }
  red[tid] = s1; __syncthreads();
  if (nl == 0) atomicAdd(&st[ST_SC_SUM + s*64 + o], red[o] + red[64+o] + red[128+o] + red[192+o]);
  __syncthreads();
  red[tid] = s2; __syncthreads();
  if (nl == 0) atomicAdd(&st[ST_SC_SQ + s*64 + o], red[o] + red[64+o] + red[128+o] + red[192+o]);
}

__global__ void k8_sc_fin(const float* __restrict__ g, const float* __restrict__ be,
                          float* __restrict__ st) {
  int i = threadIdx.x; // 192
  int s = i / 64;
  float n = s==0 ? 2048.f : (s==1 ? 1536.f : 384.f);
  float m = st[ST_SC_SUM+i]/n;
  float var = st[ST_SC_SQ+i]/n - m*m;
  float a = g[i]*rsqrtf(var + EPS_);
  st[ST_SC_A+i] = a; st[ST_SC_D+i] = be[i] - a*m;
}

// ---------------- K9: BN+ReLU -> dgcn input [node][64] ----------------
__global__ void k9_bnrelu(const float* __restrict__ y, const float* __restrict__ st,
                          float* __restrict__ x) {
  int i = blockIdx.x*256 + threadIdx.x;
  int node = i >> 6, o = i & 63;
  int nb = node % NPB_;
  int s = nb < 1024 ? 0 : (nb < 1792 ? 1 : 2);
  x[i] = fmaxf(st[ST_SC_A + s*64+o]*y[i] + st[ST_SC_D + s*64+o], 0.f);
}

// ---------------- K10: one EdgeConv layer (all scales) ----------------
__global__ __launch_bounds__(64) void k10_dgcn(
    const float* __restrict__ xin, float* __restrict__ xout,
    const int* __restrict__ edge0, const int* __restrict__ edge1, const int* __restrict__ edge2,
    const float* __restrict__ dw, const float* __restrict__ db, int layer) {
  __shared__ float xc8[8][68];
  __shared__ float xn8[8][68];
  int gn = blockIdx.x, o = threadIdx.x;
  int b = gn / NPB_, nb = gn % NPB_;
  int s, v, rb; const int *ec, *en;
  if (nb < 1024) { s = 0; v = nb; rb = b*NPB_; ec = edge0 + b*2*8192; en = ec + 8192; }
  else if (nb < 1792) { s = 1; int j = nb - 1024; int vp = j >> 8; v = j & 255;
    rb = b*NPB_ + 1024 + vp*256; ec = edge1 + ((b*3+vp)*2)*2048; en = ec + 2048; }
  else { s = 2; int j = nb - 1792; int vp = j >> 6; v = j & 63;
    rb = b*NPB_ + 1792 + vp*64; ec = edge2 + ((b*3+vp)*2)*512; en = ec + 512; }
  const float* w = dw + (s*4 + layer)*128*64;
  float bias = db[(s*4 + layer)*64 + o];
  for (int j = 0; j < 8; j++) {
    int e = v*8 + j;
    int ci = ec[e], ni = en[e];
    xc8[j][o] = xin[(size_t)(rb + ci)*64 + o];
    xn8[j][o] = xin[(size_t)(rb + ni)*64 + o];
  }
  __syncthreads();
  float acc[8];
  #pragma unroll
  for (int j = 0; j < 8; j++) acc[j] = bias;
  for (int cc = 0; cc < 64; cc += 4) {
    float wa0 = w[(cc+0)*64+o], wa1 = w[(cc+1)*64+o], wa2 = w[(cc+2)*64+o], wa3 = w[(cc+3)*64+o];
    float wb0 = w[(64+cc+0)*64+o], wb1 = w[(64+cc+1)*64+o], wb2 = w[(64+cc+2)*64+o], wb3 = w[(64+cc+3)*64+o];
    #pragma unroll
    for (int j = 0; j < 8; j++) {
      float4 xc = *(const float4*)&xc8[j][cc];
      float4 xn = *(const float4*)&xn8[j][cc];
      acc[j] += xc.x*wa0 + (xn.x-xc.x)*wb0
              + xc.y*wa1 + (xn.y-xc.y)*wb1
              + xc.z*wa2 + (xn.z-xc.z)*wb2
              + xc.w*wa3 + (xn.w-xc.w)*wb3;
    }
  }
  float m = 0.f;
  #pragma unroll
  for (int j = 0; j < 8; j++) m = fmaxf(m, fmaxf(acc[j], 0.f));
  xout[(size_t)gn*64 + o] = m;
}

// ---------------- K11: head: logits, sigmoid preds, BCE partials ----------------
__global__ __launch_bounds__(64) void k11_head(
    const float* __restrict__ x, const float* __restrict__ hw, const float* __restrict__ hb,
    const int* __restrict__ t0, const int* __restrict__ t1, const int* __restrict__ t2,
    float* __restrict__ out, float* __restrict__ st) {
  __shared__ float buf[64*65];
  int tid = threadIdx.x;
  int n0 = blockIdx.x * 64;
  for (int i = 0; i < 64; i++)
    buf[i*65 + tid] = x[(size_t)(n0 + i)*64 + tid];
  __syncthreads();
  int gn = n0 + tid;
  int b = gn / NPB_, nb = gn % NPB_;
  int s, tg;
  if (nb < 1024) { s = 0; tg = t0[b*1024 + nb]; }
  else if (nb < 1792) { s = 1; int j = nb-1024; tg = t1[(b*3 + (j>>8))*256 + (j&255)]; }
  else { s = 2; int j = nb-1792; tg = t2[(b*3 + (j>>6))*64 + (j&63)]; }
  float logit = hb[s];
  for (int c = 0; c < 64; c++) logit += buf[tid*65 + c] * hw[s*64 + c];
  out[6 + gn] = 1.f / (1.f + expf(-logit));
  float tf = (float)tg;
  float l = fmaxf(logit, 0.f) - logit*tf + log1pf(expf(-fabsf(logit)));
  float sp = tg ? l : 0.f, sn = tg ? 0.f : l;
  float cp = tg ? 1.f : 0.f, cn = 1.f - cp;
  for (int off = 32; off; off >>= 1) {
    sp += __shfl_down(sp, off);
    sn += __shfl_down(sn, off);
    cp += __shfl_down(cp, off);
    cn += __shfl_down(cn, off);
  }
  if (tid == 0) {   // block is scale-uniform (64-aligned boundaries)
    atomicAdd(&st[ST_LOSS + s*4 + 0], sp);
    atomicAdd(&st[ST_LOSS + s*4 + 1], sn);
    atomicAdd(&st[ST_LOSS + s*4 + 2], cp);
    atomicAdd(&st[ST_LOSS + s*4 + 3], cn);
  }
}

__global__ void k12_fin(const float* __restrict__ st, float* __restrict__ out) {
  int i = threadIdx.x;
  if (i < 6) {
    int s = i >> 1; int pos = !(i & 1);
    float sum = st[ST_LOSS + s*4 + (pos ? 0 : 1)];
    float cnt = st[ST_LOSS + s*4 + (pos ? 2 : 3)];
    out[i] = sum / fmaxf(cnt, 1.f);
  }
}

extern "C" void kernel_launch(void* const* d_in, const int* in_sizes, int n_in,
                              void* d_out, int out_size, void* d_ws, size_t ws_size,
                              hipStream_t stream) {
  const float* image  = (const float*)d_in[0];
  const float* bn_g   = (const float*)d_in[1];
  const float* bn_b   = (const float*)d_in[2];
  const int*   ht_idx = (const int*)  d_in[3];
  const float* ht_w   = (const float*)d_in[4];
  const float* w_conv = (const float*)d_in[5];
  const float* htbn_g = (const float*)d_in[6];
  const float* htbn_b = (const float*)d_in[7];
  const int*   sph_idx= (const int*)  d_in[8];
  const float* sph_w  = (const float*)d_in[9];
  const float* w_sc   = (const float*)d_in[10];
  const float* b_sc   = (const float*)d_in[11];
  const float* scbn_g = (const float*)d_in[12];
  const float* scbn_b = (const float*)d_in[13];
  const float* dgcn_w = (const float*)d_in[14];
  const float* dgcn_b = (const float*)d_in[15];
  const float* dgcn_hw= (const float*)d_in[16];
  const float* dgcn_hb= (const float*)d_in[17];
  const int*   ind0   = (const int*)  d_in[18];
  const int*   ind1   = (const int*)  d_in[19];
  const int*   ind2   = (const int*)  d_in[20];
  const int*   edge0  = (const int*)  d_in[21];
  const int*   edge1  = (const int*)  d_in[22];
  const int*   edge2  = (const int*)  d_in[23];
  const int*   t0     = (const int*)  d_in[24];
  const int*   t1     = (const int*)  d_in[25];
  const int*   t2     = (const int*)  d_in[26];
  float* out = (float*)d_out;

  char* ws = (char*)d_ws;
  float* x_t   = (float*)(ws);                 // 16,777,216 B
  float* ht_t  = (float*)(ws + 16777216);      // 33,914,880 B
  float* hc_t  = (float*)(ws + 50692096);      // 33,914,880 B
  float* sph_o = (float*)(ws + 84606976);      //  2,031,616 B
  float* y_sc  = (float*)(ws + 86638592);      //  1,015,808 B
  float* xdgA  = (float*)(ws + 87654400);      //  1,015,808 B
  float* xdgB  = (float*)(ws + 88670208);      //  1,015,808 B
  float* st    = (float*)(ws + 89686016);      //      6,400 B

  hipMemsetAsync(st, 0, 652*sizeof(float), stream);
  k1_img_stats<<<128, 256, 0, stream>>>(image, bn_g, bn_b, st);
  k2_bnrelu_t<<<dim3(256,4,2), 256, 0, stream>>>(image, st, x_t);
  k3_hough<<<dim3(NBINS_/2, B_), 256, 0, stream>>>(x_t, ht_idx, ht_w, ht_t);
  k4_conv<<<dim3(5,184,2), 256, 0, stream>>>(ht_t, w_conv, hc_t);
  k5_hc_stats<<<512, 256, 0, stream>>>(hc_t, st);
  k5b_hc_fin<<<1, 128, 0, stream>>>(htbn_g, htbn_b, st);
  k6_sphere<<<TOTN_, 128, 0, stream>>>(hc_t, st, sph_idx, sph_w, ind0, ind1, ind2, sph_o);
  k7_sconv<<<TOTN_/32, 256, 0, stream>>>(sph_o, w_sc, b_sc, y_sc, st);
  k8_sc_fin<<<1, 192, 0, stream>>>(scbn_g, scbn_b, st);
  k9_bnrelu<<<TOTN_*64/256, 256, 0, stream>>>(y_sc, st, xdgA);
  k10_dgcn<<<TOTN_, 64, 0, stream>>>(xdgA, xdgB, edge0, edge1, edge2, dgcn_w, dgcn_b, 0);
  k10_dgcn<<<TOTN_, 64, 0, stream>>>(xdgB, xdgA, edge0, edge1, edge2, dgcn_w, dgcn_b, 1);
  k10_dgcn<<<TOTN_, 64, 0, stream>>>(xdgA, xdgB, edge0, edge1, edge2, dgcn_w, dgcn_b, 2);
  k10_dgcn<<<TOTN_, 64, 0, stream>>>(xdgB, xdgA, edge0, edge1, edge2, dgcn_w, dgcn_b, 3);
  k11_head<<<TOTN_/64, 64, 0, stream>>>(xdgA, dgcn_hw, dgcn_hb, t0, t1, t2, out, st);
  k12_fin<<<1, 64, 0, stream>>>(st, out);
}

// Round 3
// 375.021 us; speedup vs baseline: 1.6736x; 1.6736x over previous
//
#include <hip/hip_runtime.h>
#include <math.h>

#define B_ 2
#define C_ 128
#define NPIX_ 16384
#define HTH_ 184
#define HTW_ 180
#define NBINS_ 33120
#define PH_ 186
#define PW_ 184
#define NSPH_ 16384
#define NPB_ 1984
#define TOTN_ 3968
#define EPS_ 1e-5f

// stats region layout (floats), first 652 are zeroed each launch
#define ST_HC_SUM 0
#define ST_HC_SQ  128
#define ST_SC_SUM 256
#define ST_SC_SQ  448
#define ST_LOSS   640
#define ST_IMG_A  704
#define ST_IMG_D  832
#define ST_HC_A   960
#define ST_HC_D   1088
#define ST_SC_A   1216
#define ST_SC_D   1408

typedef __attribute__((ext_vector_type(8))) short v8s;
typedef __attribute__((ext_vector_type(4))) float v4f;

__device__ inline unsigned short f2b(float f) {
  unsigned u = __builtin_bit_cast(unsigned, f);
  unsigned r = u + 0x7fffu + ((u >> 16) & 1u);
  return (unsigned short)(r >> 16);
}

// ---------------- K0: weights fp32 [tap][ci][co] -> bf16 [tap][co][ci] ----------------
__global__ void k0_wconv(const float* __restrict__ w, unsigned short* __restrict__ wtb) {
  int i = blockIdx.x*256 + threadIdx.x;   // 147456 total
  int tap = i >> 14, r = i & 16383;
  int ci = r >> 7, co = r & 127;
  wtb[tap*16384 + co*128 + ci] = f2b(w[i]);
}

// ---------------- K1: per-channel BN stats of image -> a,d ----------------
__global__ void k1_img_stats(const float* __restrict__ img, const float* __restrict__ g,
                             const float* __restrict__ be, float* __restrict__ st) {
  int c = blockIdx.x; int tid = threadIdx.x;
  float s1 = 0.f, s2 = 0.f;
  for (int i = tid; i < B_*NPIX_; i += 256) {
    int b = i >> 14, p = i & (NPIX_-1);
    float v = img[((size_t)(b*C_ + c))*NPIX_ + p];
    s1 += v; s2 += v*v;
  }
  __shared__ float r1[256], r2[256];
  r1[tid] = s1; r2[tid] = s2; __syncthreads();
  for (int off = 128; off; off >>= 1) {
    if (tid < off) { r1[tid] += r1[tid+off]; r2[tid] += r2[tid+off]; }
    __syncthreads();
  }
  if (tid == 0) {
    float n = (float)(B_*NPIX_);
    float m = r1[0]/n; float var = r2[0]/n - m*m;
    float a = g[c]*rsqrtf(var + EPS_);
    st[ST_IMG_A + c] = a;
    st[ST_IMG_D + c] = be[c] - a*m;
  }
}

// ---------------- K2: BN+ReLU + transpose NCHW -> [b][pix][c] ----------------
__global__ void k2_bnrelu_t(const float* __restrict__ img, const float* __restrict__ st,
                            float* __restrict__ xt) {
  __shared__ float tile[32*65];
  int p0 = blockIdx.x*64, c0 = blockIdx.y*32, b = blockIdx.z;
  int tid = threadIdx.x;
  for (int r = 0; r < 8; r++) {
    int flat = tid + r*256;
    int row = flat >> 6, col = flat & 63;
    int c = c0 + row;
    float v = img[((size_t)(b*C_ + c))*NPIX_ + p0 + col];
    tile[row*65 + col] = fmaxf(st[ST_IMG_A + c]*v + st[ST_IMG_D + c], 0.f);
  }
  __syncthreads();
  for (int r = 0; r < 8; r++) {
    int flat = tid + r*256;
    int pl = flat >> 5, cl = flat & 31;
    xt[((size_t)b*NPIX_ + p0 + pl)*C_ + c0 + cl] = tile[cl*65 + pl];
  }
}

// ---------------- K3: Hough gather -> padded bf16 [b][y+1][x+1][c] ----------------
__global__ void k3_hough(const float* __restrict__ xt, const int* __restrict__ hidx,
                         const float* __restrict__ hwt, unsigned short* __restrict__ htb) {
  int tid = threadIdx.x;
  int bin = blockIdx.x*2 + (tid >> 7);
  int b = blockIdx.y;
  int c = tid & 127;
  float acc = 0.f;
  #pragma unroll
  for (int k = 0; k < 8; k++) {
    int p = hidx[bin*8 + k];
    float w = hwt[bin*8 + k];
    acc += w * xt[((size_t)b*NPIX_ + p)*C_ + c];
  }
  int y = bin / HTW_, x = bin % HTW_;
  htb[(((size_t)(b*PH_ + y + 1))*PW_ + (x+1))*C_ + c] = f2b(acc);
}

// ---------------- K4: 3x3 conv as implicit GEMM, bf16 MFMA ----------------
// block: 256 thr = 4 waves; wave: 32 px x 128 co; K = 9 taps x 128 ci
__global__ __launch_bounds__(256) void k4_mfma(
    const unsigned short* __restrict__ htb, const unsigned short* __restrict__ wtb,
    float* __restrict__ hc) {
  __shared__ unsigned short wlds[128*136];   // [co][ci], row stride 136 (+8 pad)
  int tid = threadIdx.x;
  int wave = tid >> 6, lane = tid & 63;
  int quad = lane >> 4, l16 = lane & 15;
  int b = blockIdx.y;
  int p0 = blockIdx.x*128 + wave*32;
  int px0 = p0 + l16;        if (px0 > NBINS_-1) px0 = NBINS_-1;
  int px1 = p0 + 16 + l16;   if (px1 > NBINS_-1) px1 = NBINS_-1;
  int y0 = px0 / HTW_, x0c = px0 % HTW_;
  int y1 = px1 / HTW_, x1c = px1 % HTW_;
  // padded origin: unpadded (y,x) -> padded (y+dy, x+dx), dy,dx in 0..2; base at (y,x)
  size_t ab0 = (((size_t)(b*PH_ + y0))*PW_ + x0c)*C_ + quad*8;
  size_t ab1 = (((size_t)(b*PH_ + y1))*PW_ + x1c)*C_ + quad*8;
  v4f acc0[8], acc1[8];
  #pragma unroll
  for (int nt = 0; nt < 8; nt++) { acc0[nt] = (v4f){0,0,0,0}; acc1[nt] = (v4f){0,0,0,0}; }

  for (int tap = 0; tap < 9; tap++) {
    __syncthreads();
    // stage 32KB weights for this tap
    const unsigned short* wsrc = wtb + tap*16384;
    #pragma unroll
    for (int j = 0; j < 8; j++) {
      int flat = tid*64 + j*8;
      int co = flat >> 7, ci = flat & 127;
      *(v8s*)&wlds[co*136 + ci] = *(const v8s*)&wsrc[flat];
    }
    __syncthreads();
    int dy = tap / 3, dx = tap % 3;
    size_t toff = ((size_t)dy*PW_ + dx)*C_;
    #pragma unroll
    for (int kt = 0; kt < 4; kt++) {
      v8s a0 = *(const v8s*)&htb[ab0 + toff + kt*32];
      v8s a1 = *(const v8s*)&htb[ab1 + toff + kt*32];
      int ko = kt*32 + quad*8;
      #pragma unroll
      for (int nt = 0; nt < 8; nt++) {
        v8s bf = *(const v8s*)&wlds[(nt*16 + l16)*136 + ko];
        acc0[nt] = __builtin_amdgcn_mfma_f32_16x16x32_bf16(a0, bf, acc0[nt], 0, 0, 0);
        acc1[nt] = __builtin_amdgcn_mfma_f32_16x16x32_bf16(a1, bf, acc1[nt], 0, 0, 0);
      }
    }
  }
  // epilogue: D row = quad*4+reg (pixel), col = lane&15 (co)
  #pragma unroll
  for (int nt = 0; nt < 8; nt++) {
    int co = nt*16 + l16;
    #pragma unroll
    for (int reg = 0; reg < 4; reg++) {
      int m = quad*4 + reg;
      int po0 = p0 + m;
      int po1 = p0 + 16 + m;
      if (po0 < NBINS_) hc[((size_t)b*NBINS_ + po0)*C_ + co] = acc0[nt][reg];
      if (po1 < NBINS_) hc[((size_t)b*NBINS_ + po1)*C_ + co] = acc1[nt][reg];
    }
  }
}

// ---------------- K5: hc BN stats (atomic accumulate) ----------------
__global__ void k5_hc_stats(const float* __restrict__ hc, float* __restrict__ st) {
  int tid = threadIdx.x; int c = tid & 127;
  float s1 = 0.f, s2 = 0.f;
  for (int row = blockIdx.x*2 + (tid >> 7); row < B_*NBINS_; row += 1024) {
    float v = hc[(size_t)row*C_ + c];
    s1 += v; s2 += v*v;
  }
  __shared__ float r[256];
  r[tid] = s1; __syncthreads();
  if (tid < 128) atomicAdd(&st[ST_HC_SUM + c], r[tid] + r[tid+128]);
  __syncthreads();
  r[tid] = s2; __syncthreads();
  if (tid < 128) atomicAdd(&st[ST_HC_SQ + c], r[tid] + r[tid+128]);
}

__global__ void k5b_hc_fin(const float* __restrict__ g, const float* __restrict__ be,
                           float* __restrict__ st) {
  int c = threadIdx.x;
  float n = (float)(B_*NBINS_);
  float m = st[ST_HC_SUM+c]/n;
  float var = st[ST_HC_SQ+c]/n - m*m;
  float a = g[c]*rsqrtf(var + EPS_);
  st[ST_HC_A+c] = a; st[ST_HC_D+c] = be[c] - a*m;
}

// ---------------- K6: sphere gather with fused BN+ReLU of hc ----------------
__global__ void k6_sphere(const float* __restrict__ hc, const float* __restrict__ st,
                          const int* __restrict__ sph_idx, const float* __restrict__ sph_w,
                          const int* __restrict__ ind0, const int* __restrict__ ind1,
                          const int* __restrict__ ind2, float* __restrict__ out) {
  int gn = blockIdx.x; int c = threadIdx.x;
  int b = gn / NPB_, nb = gn % NPB_;
  int v;
  if (nb < 1024) v = ind0[b*1024 + nb];
  else if (nb < 1792) v = ind1[b*768 + nb - 1024];
  else v = ind2[b*192 + nb - 1792];
  float a = st[ST_HC_A + c], d = st[ST_HC_D + c];
  float acc = 0.f;
  #pragma unroll
  for (int k = 0; k < 16; k++) {
    int mi = sph_idx[v*16 + k];
    float mw = sph_w[v*16 + k];
    float hv = hc[((size_t)b*NBINS_ + mi)*C_ + c];
    acc += mw * fmaxf(a*hv + d, 0.f);
  }
  out[(size_t)gn*C_ + c] = acc;
}

// ---------------- K7: 1x1 sconv [128->64] + BN stat accumulation ----------------
__global__ __launch_bounds__(256) void k7_sconv(
    const float* __restrict__ xin, const float* __restrict__ w_sc,
    const float* __restrict__ b_sc, float* __restrict__ y, float* __restrict__ st) {
  __shared__ float xs[32*128];
  __shared__ float wT[128*65];
  __shared__ float red[256];
  int tid = threadIdx.x;
  int gn0 = blockIdx.x * 32;
  int nb = gn0 % NPB_;
  int s = nb < 1024 ? 0 : (nb < 1792 ? 1 : 2);   // block scale-uniform (32-aligned)
  for (int r = 0; r < 16; r++) {
    int flat = tid + r*256;
    xs[flat] = xin[(size_t)gn0*C_ + flat];
  }
  for (int r = 0; r < 32; r++) {
    int flat = tid + r*256;
    int o = flat >> 7, cc = flat & 127;
    wT[cc*65 + o] = w_sc[(s*64 + o)*C_ + cc];
  }
  __syncthreads();
  int o = tid & 63, nl = tid >> 6;
  float bias = b_sc[s*64 + o];
  float acc[8];
  #pragma unroll
  for (int i = 0; i < 8; i++) acc[i] = bias;
  for (int cc = 0; cc < 128; cc++) {
    float wv = wT[cc*65 + o];
    #pragma unroll
    for (int i = 0; i < 8; i++)
      acc[i] += xs[(nl*8 + i)*128 + cc] * wv;
  }
  float s1 = 0.f, s2 = 0.f;
  #pragma unroll
  for (int i = 0; i < 8; i++) {
    y[(size_t)(gn0 + nl*8 + i)*64 + o] = acc[i];
    s1 += acc[i]; s2 += acc[i]*acc[i];
  }
  red[tid] = s1; __syncthreads();
  if (nl == 0) atomicAdd(&st[ST_SC_SUM + s*64 + o], red[o] + red[64+o] + red[128+o] + red[192+o]);
  __syncthreads();
  red[tid] = s2; __syncthreads();
  if (nl == 0) atomicAdd(&st[ST_SC_SQ + s*64 + o], red[o] + red[64+o] + red[128+o] + red[192+o]);
}

__global__ void k8_sc_fin(const float* __restrict__ g, const float* __restrict__ be,
                          float* __restrict__ st) {
  int i = threadIdx.x; // 192
  int s = i / 64;
  float n = s==0 ? 2048.f : (s==1 ? 1536.f : 384.f);
  float m = st[ST_SC_SUM+i]/n;
  float var = st[ST_SC_SQ+i]/n - m*m;
  float a = g[i]*rsqrtf(var + EPS_);
  st[ST_SC_A+i] = a; st[ST_SC_D+i] = be[i] - a*m;
}

// ---------------- K9: BN+ReLU -> dgcn input [node][64] ----------------
__global__ void k9_bnrelu(const float* __restrict__ y, const float* __restrict__ st,
                          float* __restrict__ x) {
  int i = blockIdx.x*256 + threadIdx.x;
  int node = i >> 6, o = i & 63;
  int nb = node % NPB_;
  int s = nb < 1024 ? 0 : (nb < 1792 ? 1 : 2);
  x[i] = fmaxf(st[ST_SC_A + s*64+o]*y[i] + st[ST_SC_D + s*64+o], 0.f);
}

// ---------------- K10: one EdgeConv layer (all scales) ----------------
__global__ __launch_bounds__(64) void k10_dgcn(
    const float* __restrict__ xin, float* __restrict__ xout,
    const int* __restrict__ edge0, const int* __restrict__ edge1, const int* __restrict__ edge2,
    const float* __restrict__ dw, const float* __restrict__ db, int layer) {
  __shared__ float xc8[8][68];
  __shared__ float xn8[8][68];
  int gn = blockIdx.x, o = threadIdx.x;
  int b = gn / NPB_, nb = gn % NPB_;
  int s, v, rb; const int *ec, *en;
  if (nb < 1024) { s = 0; v = nb; rb = b*NPB_; ec = edge0 + b*2*8192; en = ec + 8192; }
  else if (nb < 1792) { s = 1; int j = nb - 1024; int vp = j >> 8; v = j & 255;
    rb = b*NPB_ + 1024 + vp*256; ec = edge1 + ((b*3+vp)*2)*2048; en = ec + 2048; }
  else { s = 2; int j = nb - 1792; int vp = j >> 6; v = j & 63;
    rb = b*NPB_ + 1792 + vp*64; ec = edge2 + ((b*3+vp)*2)*512; en = ec + 512; }
  const float* w = dw + (s*4 + layer)*128*64;
  float bias = db[(s*4 + layer)*64 + o];
  for (int j = 0; j < 8; j++) {
    int e = v*8 + j;
    int ci = ec[e], ni = en[e];
    xc8[j][o] = xin[(size_t)(rb + ci)*64 + o];
    xn8[j][o] = xin[(size_t)(rb + ni)*64 + o];
  }
  __syncthreads();
  float acc[8];
  #pragma unroll
  for (int j = 0; j < 8; j++) acc[j] = bias;
  for (int cc = 0; cc < 64; cc += 4) {
    float wa0 = w[(cc+0)*64+o], wa1 = w[(cc+1)*64+o], wa2 = w[(cc+2)*64+o], wa3 = w[(cc+3)*64+o];
    float wb0 = w[(64+cc+0)*64+o], wb1 = w[(64+cc+1)*64+o], wb2 = w[(64+cc+2)*64+o], wb3 = w[(64+cc+3)*64+o];
    #pragma unroll
    for (int j = 0; j < 8; j++) {
      float4 xc = *(const float4*)&xc8[j][cc];
      float4 xn = *(const float4*)&xn8[j][cc];
      acc[j] += xc.x*wa0 + (xn.x-xc.x)*wb0
              + xc.y*wa1 + (xn.y-xc.y)*wb1
              + xc.z*wa2 + (xn.z-xc.z)*wb2
              + xc.w*wa3 + (xn.w-xc.w)*wb3;
    }
  }
  float m = 0.f;
  #pragma unroll
  for (int j = 0; j < 8; j++) m = fmaxf(m, fmaxf(acc[j], 0.f));
  xout[(size_t)gn*64 + o] = m;
}

// ---------------- K11: head: logits, sigmoid preds, BCE partials ----------------
__global__ __launch_bounds__(64) void k11_head(
    const float* __restrict__ x, const float* __restrict__ hw, const float* __restrict__ hb,
    const int* __restrict__ t0, const int* __restrict__ t1, const int* __restrict__ t2,
    float* __restrict__ out, float* __restrict__ st) {
  __shared__ float buf[64*65];
  int tid = threadIdx.x;
  int n0 = blockIdx.x * 64;
  for (int i = 0; i < 64; i++)
    buf[i*65 + tid] = x[(size_t)(n0 + i)*64 + tid];
  __syncthreads();
  int gn = n0 + tid;
  int b = gn / NPB_, nb = gn % NPB_;
  int s, tg;
  if (nb < 1024) { s = 0; tg = t0[b*1024 + nb]; }
  else if (nb < 1792) { s = 1; int j = nb-1024; tg = t1[(b*3 + (j>>8))*256 + (j&255)]; }
  else { s = 2; int j = nb-1792; tg = t2[(b*3 + (j>>6))*64 + (j&63)]; }
  float logit = hb[s];
  for (int c = 0; c < 64; c++) logit += buf[tid*65 + c] * hw[s*64 + c];
  out[6 + gn] = 1.f / (1.f + expf(-logit));
  float tf = (float)tg;
  float l = fmaxf(logit, 0.f) - logit*tf + log1pf(expf(-fabsf(logit)));
  float sp = tg ? l : 0.f, sn = tg ? 0.f : l;
  float cp = tg ? 1.f : 0.f, cn = 1.f - cp;
  for (int off = 32; off; off >>= 1) {
    sp += __shfl_down(sp, off);
    sn += __shfl_down(sn, off);
    cp += __shfl_down(cp, off);
    cn += __shfl_down(cn, off);
  }
  if (tid == 0) {   // block is scale-uniform (64-aligned boundaries)
    atomicAdd(&st[ST_LOSS + s*4 + 0], sp);
    atomicAdd(&st[ST_LOSS + s*4 + 1], sn);
    atomicAdd(&st[ST_LOSS + s*4 + 2], cp);
    atomicAdd(&st[ST_LOSS + s*4 + 3], cn);
  }
}

__global__ void k12_fin(const float* __restrict__ st, float* __restrict__ out) {
  int i = threadIdx.x;
  if (i < 6) {
    int s = i >> 1; int pos = !(i & 1);
    float sum = st[ST_LOSS + s*4 + (pos ? 0 : 1)];
    float cnt = st[ST_LOSS + s*4 + (pos ? 2 : 3)];
    out[i] = sum / fmaxf(cnt, 1.f);
  }
}

extern "C" void kernel_launch(void* const* d_in, const int* in_sizes, int n_in,
                              void* d_out, int out_size, void* d_ws, size_t ws_size,
                              hipStream_t stream) {
  const float* image  = (const float*)d_in[0];
  const float* bn_g   = (const float*)d_in[1];
  const float* bn_b   = (const float*)d_in[2];
  const int*   ht_idx = (const int*)  d_in[3];
  const float* ht_w   = (const float*)d_in[4];
  const float* w_conv = (const float*)d_in[5];
  const float* htbn_g = (const float*)d_in[6];
  const float* htbn_b = (const float*)d_in[7];
  const int*   sph_idx= (const int*)  d_in[8];
  const float* sph_w  = (const float*)d_in[9];
  const float* w_sc   = (const float*)d_in[10];
  const float* b_sc   = (const float*)d_in[11];
  const float* scbn_g = (const float*)d_in[12];
  const float* scbn_b = (const float*)d_in[13];
  const float* dgcn_w = (const float*)d_in[14];
  const float* dgcn_b = (const float*)d_in[15];
  const float* dgcn_hw= (const float*)d_in[16];
  const float* dgcn_hb= (const float*)d_in[17];
  const int*   ind0   = (const int*)  d_in[18];
  const int*   ind1   = (const int*)  d_in[19];
  const int*   ind2   = (const int*)  d_in[20];
  const int*   edge0  = (const int*)  d_in[21];
  const int*   edge1  = (const int*)  d_in[22];
  const int*   edge2  = (const int*)  d_in[23];
  const int*   t0     = (const int*)  d_in[24];
  const int*   t1     = (const int*)  d_in[25];
  const int*   t2     = (const int*)  d_in[26];
  float* out = (float*)d_out;

  char* ws = (char*)d_ws;
  float*          x_t   = (float*)(ws);                       // 16,777,216 B
  unsigned short* htb   = (unsigned short*)(ws + 16777216);   // 17,522,688 B (padded bf16)
  float*          hc_t  = (float*)(ws + 34299904);            // 33,914,880 B
  unsigned short* wtb   = (unsigned short*)(ws + 68214784);   //    294,912 B
  float*          sph_o = (float*)(ws + 68509696);            //  2,031,616 B
  float*          y_sc  = (float*)(ws + 70541312);            //  1,015,808 B
  float*          xdgA  = (float*)(ws + 71557120);            //  1,015,808 B
  float*          xdgB  = (float*)(ws + 72572928);            //  1,015,808 B
  float*          st    = (float*)(ws + 73588736);            //      6,400 B

  hipMemsetAsync(st, 0, 652*sizeof(float), stream);
  hipMemsetAsync(htb, 0, 17522688, stream);                  // zero padding borders
  k0_wconv<<<576, 256, 0, stream>>>(w_conv, wtb);
  k1_img_stats<<<128, 256, 0, stream>>>(image, bn_g, bn_b, st);
  k2_bnrelu_t<<<dim3(256,4,2), 256, 0, stream>>>(image, st, x_t);
  k3_hough<<<dim3(NBINS_/2, B_), 256, 0, stream>>>(x_t, ht_idx, ht_w, htb);
  k4_mfma<<<dim3(259, 2), 256, 0, stream>>>(htb, wtb, hc_t);
  k5_hc_stats<<<512, 256, 0, stream>>>(hc_t, st);
  k5b_hc_fin<<<1, 128, 0, stream>>>(htbn_g, htbn_b, st);
  k6_sphere<<<TOTN_, 128, 0, stream>>>(hc_t, st, sph_idx, sph_w, ind0, ind1, ind2, sph_o);
  k7_sconv<<<TOTN_/32, 256, 0, stream>>>(sph_o, w_sc, b_sc, y_sc, st);
  k8_sc_fin<<<1, 192, 0, stream>>>(scbn_g, scbn_b, st);
  k9_bnrelu<<<TOTN_*64/256, 256, 0, stream>>>(y_sc, st, xdgA);
  k10_dgcn<<<TOTN_, 64, 0, stream>>>(xdgA, xdgB, edge0, edge1, edge2, dgcn_w, dgcn_b, 0);
  k10_dgcn<<<TOTN_, 64, 0, stream>>>(xdgB, xdgA, edge0, edge1, edge2, dgcn_w, dgcn_b, 1);
  k10_dgcn<<<TOTN_, 64, 0, stream>>>(xdgA, xdgB, edge0, edge1, edge2, dgcn_w, dgcn_b, 2);
  k10_dgcn<<<TOTN_, 64, 0, stream>>>(xdgB, xdgA, edge0, edge1, edge2, dgcn_w, dgcn_b, 3);
  k11_head<<<TOTN_/64, 64, 0, stream>>>(xdgA, dgcn_hw, dgcn_hb, t0, t1, t2, out, st);
  k12_fin<<<1, 64, 0, stream>>>(st, out);
}